// Round 1
// baseline (5210.075 us; speedup 1.0000x reference)
//
#include <hip/hip_runtime.h>

// Convolution_1228360646680 — equivariant graph conv
// N=25000 nodes, E=400000 edges, MUL=32, NSC=8, HID=64
//
// Pipeline:
//   prep:    stage scaled Wfc1 (8x64) and transposed+scaled Wfc2^T (128x64) into ws
//   node_in: xsv1[n][128] = {xs1 (32), xv1 interleaved (96)} = a[n]/sqrt(32) * (x @ w1)
//   edge:    per-edge MLP (scalar-path weights) -> 256 features -> atomicAdd into mid[N][256]
//   node_out: out[n][128] = b[n]*inv2*0.25 * (mid @ w2)

#define NMUL 32

__global__ __launch_bounds__(256) void prep_kernel(
    const float* __restrict__ Wfc1, const float* __restrict__ Wfc2,
    float* __restrict__ W1s, float* __restrict__ W2T)
{
    int t = blockIdx.x * 256 + threadIdx.x;
    const float inv_sqrt_nsc = 0.35355339059327373f; // 1/sqrt(8)
    if (t < 8 * 64) W1s[t] = Wfc1[t] * inv_sqrt_nsc;
    if (t < 64 * 128) {
        int r = t >> 7, c = t & 127;
        W2T[c * 64 + r] = Wfc2[t] * 0.125f;          // 1/sqrt(64)
    }
}

__global__ __launch_bounds__(256) void node_in_kernel(
    const float* __restrict__ node_input, const float* __restrict__ attr_in,
    const float* __restrict__ w1s, const float* __restrict__ w1v,
    float* __restrict__ xsv1, int n_nodes)
{
    __shared__ float sWs[1024], sWv[1024], srow[2][128];
    for (int k = threadIdx.x; k < 1024; k += 256) { sWs[k] = w1s[k]; sWv[k] = w1v[k]; }
    int j = threadIdx.x & 127;
    int half = threadIdx.x >> 7;
    int w = 0, i = 0;
    if (j >= 32) { int jj = j - 32; w = jj / 3; i = jj - 3 * w; }
    const float inv1 = 0.17677669529663687f; // 1/sqrt(32)
    for (int base = blockIdx.x * 2; base < n_nodes; base += gridDim.x * 2) {
        int n = base + half;
        __syncthreads();
        if (n < n_nodes) srow[half][j] = node_input[(size_t)n * 128 + j];
        __syncthreads();
        if (n < n_nodes) {
            float acc = 0.0f;
            if (j < 32) {
                #pragma unroll
                for (int u = 0; u < 32; u++) acc += srow[half][u] * sWs[u * 32 + j];
            } else {
                #pragma unroll
                for (int u = 0; u < 32; u++) acc += srow[half][32 + 3 * u + i] * sWv[u * 32 + w];
            }
            xsv1[(size_t)n * 128 + j] = acc * (attr_in[n] * inv1);
        }
    }
}

__global__ __launch_bounds__(256) void edge_kernel(
    const float* __restrict__ xsv1, const int* __restrict__ esrc, const int* __restrict__ edst,
    const float* __restrict__ eattr, const float* __restrict__ escal,
    const float* __restrict__ W1s, const float* __restrict__ W2T,
    float* __restrict__ mid, int n_edges)
{
    int e = blockIdx.x * 256 + threadIdx.x;
    if (e >= n_edges) return;
    const float4 qa = *reinterpret_cast<const float4*>(escal + (size_t)e * 8);
    const float4 qb = *reinterpret_cast<const float4*>(escal + (size_t)e * 8 + 4);
    float h[64];
    #pragma unroll
    for (int t = 0; t < 64; t++) {
        float acc = qa.x * W1s[t]       + qa.y * W1s[64 + t]
                  + qa.z * W1s[128 + t] + qa.w * W1s[192 + t]
                  + qb.x * W1s[256 + t] + qb.y * W1s[320 + t]
                  + qb.z * W1s[384 + t] + qb.w * W1s[448 + t];
        h[t] = acc / (1.0f + __expf(-acc));   // silu
    }
    int src = esrc[e], dst = edst[e];
    const float4 ea = *reinterpret_cast<const float4*>(eattr + (size_t)e * 4);
    const float ys = ea.x, yv0 = ea.y, yv1 = ea.z, yv2 = ea.w;
    const float* __restrict__ nb = xsv1 + (size_t)src * 128;
    float* __restrict__ op = mid + (size_t)dst * 256;
    const float inv_sqrt3 = 0.5773502691896258f;
    for (int u = 0; u < 32; u++) {
        float w0 = 0.f, w1 = 0.f, w2 = 0.f, w3 = 0.f;
        const float* __restrict__ r0 = W2T + (size_t)u * 64;
        const float* __restrict__ r1 = W2T + (size_t)(32 + u) * 64;
        const float* __restrict__ r2 = W2T + (size_t)(64 + u) * 64;
        const float* __restrict__ r3 = W2T + (size_t)(96 + u) * 64;
        #pragma unroll
        for (int t = 0; t < 64; t++) {
            float hv = h[t];
            w0 += hv * r0[t];
            w1 += hv * r1[t];
            w2 += hv * r2[t];
            w3 += hv * r3[t];
        }
        float es  = nb[u];
        float ev0 = nb[32 + 3 * u], ev1 = nb[33 + 3 * u], ev2 = nb[34 + 3 * u];
        atomicAdd(op + u,       w0 * es * ys);
        atomicAdd(op + 32 + u,  w3 * (ev0 * yv0 + ev1 * yv1 + ev2 * yv2) * inv_sqrt3);
        float a1 = w1 * es;
        atomicAdd(op + 64 + 3 * u, a1 * yv0);
        atomicAdd(op + 65 + 3 * u, a1 * yv1);
        atomicAdd(op + 66 + 3 * u, a1 * yv2);
        float a2 = w2 * ys;
        atomicAdd(op + 160 + 3 * u, a2 * ev0);
        atomicAdd(op + 161 + 3 * u, a2 * ev1);
        atomicAdd(op + 162 + 3 * u, a2 * ev2);
    }
}

__global__ __launch_bounds__(256) void node_out_kernel(
    const float* __restrict__ mid, const float* __restrict__ attr_out,
    const float* __restrict__ w2s, const float* __restrict__ w2v,
    float* __restrict__ out, int n_nodes)
{
    __shared__ float sS0[1024], sS1[1024], sV0[1024], sV1[1024];
    for (int k = threadIdx.x; k < 1024; k += 256) {
        sS0[k] = w2s[k]; sS1[k] = w2s[1024 + k];
        sV0[k] = w2v[k]; sV1[k] = w2v[1024 + k];
    }
    __syncthreads();
    int j = threadIdx.x & 127;
    int half = threadIdx.x >> 7;
    int w = 0, i = 0;
    if (j >= 32) { int jj = j - 32; w = jj / 3; i = jj - 3 * w; }
    const float scale = 0.125f * 0.25f; // 1/sqrt(64) * 1/sqrt(16)
    for (int base = blockIdx.x * 2; base < n_nodes; base += gridDim.x * 2) {
        int n = base + half;
        if (n >= n_nodes) continue;
        const float* __restrict__ mr = mid + (size_t)n * 256;
        float acc = 0.0f;
        if (j < 32) {
            #pragma unroll
            for (int u = 0; u < 32; u++)
                acc += mr[u] * sS0[u * 32 + j] + mr[32 + u] * sS1[u * 32 + j];
        } else {
            #pragma unroll
            for (int u = 0; u < 32; u++)
                acc += mr[64 + 3 * u + i] * sV0[u * 32 + w] + mr[160 + 3 * u + i] * sV1[u * 32 + w];
        }
        out[(size_t)n * 128 + j] = acc * (attr_out[n] * scale);
    }
}

extern "C" void kernel_launch(void* const* d_in, const int* in_sizes, int n_in,
                              void* d_out, int out_size, void* d_ws, size_t ws_size,
                              hipStream_t stream)
{
    const float* node_input = (const float*)d_in[0];
    const float* attr_in    = (const float*)d_in[1];
    const float* attr_out   = (const float*)d_in[2];
    const int*   esrc       = (const int*)d_in[3];
    const int*   edst       = (const int*)d_in[4];
    const float* eattr      = (const float*)d_in[5];
    const float* escal      = (const float*)d_in[6];
    const float* w1s        = (const float*)d_in[7];
    const float* w1v        = (const float*)d_in[8];
    const float* Wfc1       = (const float*)d_in[9];
    const float* Wfc2       = (const float*)d_in[10];
    const float* w2s        = (const float*)d_in[11];
    const float* w2v        = (const float*)d_in[12];
    float* out = (float*)d_out;

    int n_nodes = in_sizes[0] / 128;
    int n_edges = in_sizes[3];

    float* ws   = (float*)d_ws;
    float* mid  = ws;                                   // n_nodes*256
    float* xsv1 = mid + (size_t)n_nodes * 256;          // n_nodes*128
    float* W1s  = xsv1 + (size_t)n_nodes * 128;         // 512
    float* W2T  = W1s + 512;                            // 8192

    hipMemsetAsync(mid, 0, (size_t)n_nodes * 256 * sizeof(float), stream);
    prep_kernel<<<32, 256, 0, stream>>>(Wfc1, Wfc2, W1s, W2T);
    node_in_kernel<<<2048, 256, 0, stream>>>(node_input, attr_in, w1s, w1v, xsv1, n_nodes);
    edge_kernel<<<(n_edges + 255) / 256, 256, 0, stream>>>(xsv1, esrc, edst, eattr, escal,
                                                           W1s, W2T, mid, n_edges);
    node_out_kernel<<<2048, 256, 0, stream>>>(mid, attr_out, w2s, w2v, out, n_nodes);
}

// Round 2
// 664.003 us; speedup vs baseline: 7.8465x; 7.8465x over previous
//
#include <hip/hip_runtime.h>

// Convolution_1228360646680 — equivariant graph conv, CSR-gather version
// N=25000, E=400000, MUL=32, NSC=8, HID=64
//
// Pipeline:
//   prep:      stage scaled Wfc1 (8x64) and transposed+scaled Wfc2^T (128x64)
//   node_in:   xsv1[n][128] = a[n]/sqrt(32) * (x @ w1)   {xs1 | xv1 interleaved}
//   CSR build: count -> scan -> scatter  (edge ids sorted by dst)
//   edge_mlp:  per-edge MLP -> w[e][128] stored bf16 (no atomics)
//   gather:    block per node, thread per feature, register accumulate -> mid[n][256]
//   node_out:  out[n][128] = b[n]*inv2/sqrt(16) * (mid @ w2)
// Fallback to atomic scatter-add if ws_size too small for wbuf.

__device__ __forceinline__ unsigned bf16r(float x) {
    unsigned u = __float_as_uint(x);
    return (u + 0x7fffu + ((u >> 16) & 1u)) >> 16;   // RNE
}
__device__ __forceinline__ float bf16tof(unsigned short v) {
    return __uint_as_float(((unsigned)v) << 16);
}

__global__ __launch_bounds__(256) void prep_kernel(
    const float* __restrict__ Wfc1, const float* __restrict__ Wfc2,
    float* __restrict__ W1s, float* __restrict__ W2T)
{
    int t = blockIdx.x * 256 + threadIdx.x;
    const float inv_sqrt_nsc = 0.35355339059327373f; // 1/sqrt(8)
    if (t < 8 * 64) W1s[t] = Wfc1[t] * inv_sqrt_nsc;
    if (t < 64 * 128) {
        int r = t >> 7, c = t & 127;
        W2T[c * 64 + r] = Wfc2[t] * 0.125f;          // 1/sqrt(64)
    }
}

__global__ __launch_bounds__(256) void node_in_kernel(
    const float* __restrict__ node_input, const float* __restrict__ attr_in,
    const float* __restrict__ w1s, const float* __restrict__ w1v,
    float* __restrict__ xsv1, int n_nodes)
{
    __shared__ float sWs[1024], sWv[1024], srow[2][128];
    for (int k = threadIdx.x; k < 1024; k += 256) { sWs[k] = w1s[k]; sWv[k] = w1v[k]; }
    int j = threadIdx.x & 127;
    int half = threadIdx.x >> 7;
    int w = 0, i = 0;
    if (j >= 32) { int jj = j - 32; w = jj / 3; i = jj - 3 * w; }
    const float inv1 = 0.17677669529663687f; // 1/sqrt(32)
    for (int base = blockIdx.x * 2; base < n_nodes; base += gridDim.x * 2) {
        int n = base + half;
        __syncthreads();
        if (n < n_nodes) srow[half][j] = node_input[(size_t)n * 128 + j];
        __syncthreads();
        if (n < n_nodes) {
            float acc = 0.0f;
            if (j < 32) {
                #pragma unroll
                for (int u = 0; u < 32; u++) acc += srow[half][u] * sWs[u * 32 + j];
            } else {
                #pragma unroll
                for (int u = 0; u < 32; u++) acc += srow[half][32 + 3 * u + i] * sWv[u * 32 + w];
            }
            xsv1[(size_t)n * 128 + j] = acc * (attr_in[n] * inv1);
        }
    }
}

// ---------------- CSR build ----------------
__global__ __launch_bounds__(256) void count_kernel(
    const int* __restrict__ edst, int* __restrict__ counts, int n_edges)
{
    int e = blockIdx.x * 256 + threadIdx.x;
    if (e < n_edges) atomicAdd(&counts[edst[e]], 1);
}

__global__ __launch_bounds__(1024) void scan_kernel(
    const int* __restrict__ counts, int* __restrict__ offs, int* __restrict__ cursor, int n)
{
    __shared__ int part[1024];
    int tid = threadIdx.x;
    int chunk = (n + 1023) / 1024;
    int begin = tid * chunk;
    int end = begin + chunk; if (end > n) end = n;
    int s = 0;
    for (int i = begin; i < end; i++) s += counts[i];
    part[tid] = s;
    __syncthreads();
    for (int off = 1; off < 1024; off <<= 1) {
        int v = (tid >= off) ? part[tid - off] : 0;
        __syncthreads();
        part[tid] += v;
        __syncthreads();
    }
    int base = (tid == 0) ? 0 : part[tid - 1];
    for (int i = begin; i < end; i++) {
        offs[i] = base; cursor[i] = base;
        base += counts[i];
    }
    if (tid == 1023) offs[n] = part[1023];
}

__global__ __launch_bounds__(256) void scatter_kernel(
    const int* __restrict__ edst, int* __restrict__ cursor, int* __restrict__ elist, int n_edges)
{
    int e = blockIdx.x * 256 + threadIdx.x;
    if (e < n_edges) {
        int p = atomicAdd(&cursor[edst[e]], 1);
        elist[p] = e;
    }
}

// ---------------- edge MLP -> bf16 w rows ----------------
__global__ __launch_bounds__(256) void edge_mlp_kernel(
    const float* __restrict__ escal,
    const float* __restrict__ W1s, const float* __restrict__ W2T,
    unsigned short* __restrict__ wbuf, int n_edges)
{
    int e = blockIdx.x * 256 + threadIdx.x;
    if (e >= n_edges) return;
    const float4 qa = *reinterpret_cast<const float4*>(escal + (size_t)e * 8);
    const float4 qb = *reinterpret_cast<const float4*>(escal + (size_t)e * 8 + 4);
    float h[64];
    #pragma unroll
    for (int t = 0; t < 64; t++) {
        float acc = qa.x * W1s[t]       + qa.y * W1s[64 + t]
                  + qa.z * W1s[128 + t] + qa.w * W1s[192 + t]
                  + qb.x * W1s[256 + t] + qb.y * W1s[320 + t]
                  + qb.z * W1s[384 + t] + qb.w * W1s[448 + t];
        h[t] = acc / (1.0f + __expf(-acc));   // silu
    }
    unsigned short* op = wbuf + (size_t)e * 128;
    for (int c = 0; c < 32; c++) {
        float a0 = 0.f, a1 = 0.f, a2 = 0.f, a3 = 0.f;
        const float* __restrict__ r0 = W2T + (size_t)(4 * c) * 64;
        const float* __restrict__ r1 = r0 + 64;
        const float* __restrict__ r2 = r0 + 128;
        const float* __restrict__ r3 = r0 + 192;
        #pragma unroll
        for (int t = 0; t < 64; t++) {
            float hv = h[t];
            a0 += hv * r0[t]; a1 += hv * r1[t];
            a2 += hv * r2[t]; a3 += hv * r3[t];
        }
        unsigned p0 = bf16r(a0) | (bf16r(a1) << 16);
        unsigned p1 = bf16r(a2) | (bf16r(a3) << 16);
        *reinterpret_cast<uint2*>(op + 4 * c) = make_uint2(p0, p1);
    }
}

// ---------------- gather: block per node, thread per feature ----------------
__global__ __launch_bounds__(256) void gather_kernel(
    const unsigned short* __restrict__ wbuf, const float* __restrict__ xsv1,
    const int* __restrict__ esrc, const float* __restrict__ eattr,
    const int* __restrict__ offs, const int* __restrict__ elist,
    float* __restrict__ mid, int n_nodes)
{
    int n = blockIdx.x;
    if (n >= n_nodes) return;
    int j = threadIdx.x;
    int kind, u = 0, i = 0, col;
    if (j < 32)        { kind = 0; u = j;       col = j; }
    else if (j < 64)   { kind = 1; u = j - 32;  col = 96 + u; }
    else if (j < 160)  { int q = j - 64;  u = q / 3; i = q - 3 * u; kind = 2; col = 32 + u; }
    else               { int q = j - 160; u = q / 3; i = q - 3 * u; kind = 3; col = 64 + u; }
    const float inv_sqrt3 = 0.5773502691896258f;
    int start = offs[n], end = offs[n + 1];
    float acc = 0.0f;
    for (int k = start; k < end; k++) {
        int e = elist[k];
        int src = esrc[e];
        const float4 ea = *reinterpret_cast<const float4*>(eattr + (size_t)e * 4);
        float wv = bf16tof(wbuf[(size_t)e * 128 + col]);
        const float* __restrict__ nb = xsv1 + (size_t)src * 128;
        float contrib;
        if (kind == 0) {
            contrib = wv * nb[u] * ea.x;
        } else if (kind == 1) {
            contrib = wv * (nb[32 + 3 * u] * ea.y + nb[33 + 3 * u] * ea.z + nb[34 + 3 * u] * ea.w) * inv_sqrt3;
        } else if (kind == 2) {
            float yvi = (i == 0) ? ea.y : (i == 1) ? ea.z : ea.w;
            contrib = wv * nb[u] * yvi;
        } else {
            contrib = wv * ea.x * nb[32 + 3 * u + i];
        }
        acc += contrib;
    }
    mid[(size_t)n * 256 + j] = acc;
}

// ---------------- fallback atomic edge kernel (ws too small) ----------------
__global__ __launch_bounds__(256) void edge_kernel_atomic(
    const float* __restrict__ xsv1, const int* __restrict__ esrc, const int* __restrict__ edst,
    const float* __restrict__ eattr, const float* __restrict__ escal,
    const float* __restrict__ W1s, const float* __restrict__ W2T,
    float* __restrict__ mid, int n_edges)
{
    int e = blockIdx.x * 256 + threadIdx.x;
    if (e >= n_edges) return;
    const float4 qa = *reinterpret_cast<const float4*>(escal + (size_t)e * 8);
    const float4 qb = *reinterpret_cast<const float4*>(escal + (size_t)e * 8 + 4);
    float h[64];
    #pragma unroll
    for (int t = 0; t < 64; t++) {
        float acc = qa.x * W1s[t]       + qa.y * W1s[64 + t]
                  + qa.z * W1s[128 + t] + qa.w * W1s[192 + t]
                  + qb.x * W1s[256 + t] + qb.y * W1s[320 + t]
                  + qb.z * W1s[384 + t] + qb.w * W1s[448 + t];
        h[t] = acc / (1.0f + __expf(-acc));
    }
    int src = esrc[e], dst = edst[e];
    const float4 ea = *reinterpret_cast<const float4*>(eattr + (size_t)e * 4);
    const float ys = ea.x, yv0 = ea.y, yv1 = ea.z, yv2 = ea.w;
    const float* __restrict__ nb = xsv1 + (size_t)src * 128;
    float* __restrict__ op = mid + (size_t)dst * 256;
    const float inv_sqrt3 = 0.5773502691896258f;
    for (int u = 0; u < 32; u++) {
        float w0 = 0.f, w1 = 0.f, w2 = 0.f, w3 = 0.f;
        const float* __restrict__ r0 = W2T + (size_t)u * 64;
        const float* __restrict__ r1 = W2T + (size_t)(32 + u) * 64;
        const float* __restrict__ r2 = W2T + (size_t)(64 + u) * 64;
        const float* __restrict__ r3 = W2T + (size_t)(96 + u) * 64;
        #pragma unroll
        for (int t = 0; t < 64; t++) {
            float hv = h[t];
            w0 += hv * r0[t]; w1 += hv * r1[t]; w2 += hv * r2[t]; w3 += hv * r3[t];
        }
        float es  = nb[u];
        float ev0 = nb[32 + 3 * u], ev1 = nb[33 + 3 * u], ev2 = nb[34 + 3 * u];
        atomicAdd(op + u,      w0 * es * ys);
        atomicAdd(op + 32 + u, w3 * (ev0 * yv0 + ev1 * yv1 + ev2 * yv2) * inv_sqrt3);
        float a1 = w1 * es;
        atomicAdd(op + 64 + 3 * u, a1 * yv0);
        atomicAdd(op + 65 + 3 * u, a1 * yv1);
        atomicAdd(op + 66 + 3 * u, a1 * yv2);
        float a2 = w2 * ys;
        atomicAdd(op + 160 + 3 * u, a2 * ev0);
        atomicAdd(op + 161 + 3 * u, a2 * ev1);
        atomicAdd(op + 162 + 3 * u, a2 * ev2);
    }
}

__global__ __launch_bounds__(256) void node_out_kernel(
    const float* __restrict__ mid, const float* __restrict__ attr_out,
    const float* __restrict__ w2s, const float* __restrict__ w2v,
    float* __restrict__ out, int n_nodes)
{
    __shared__ float sS0[1024], sS1[1024], sV0[1024], sV1[1024];
    for (int k = threadIdx.x; k < 1024; k += 256) {
        sS0[k] = w2s[k]; sS1[k] = w2s[1024 + k];
        sV0[k] = w2v[k]; sV1[k] = w2v[1024 + k];
    }
    __syncthreads();
    int j = threadIdx.x & 127;
    int half = threadIdx.x >> 7;
    int w = 0, i = 0;
    if (j >= 32) { int jj = j - 32; w = jj / 3; i = jj - 3 * w; }
    const float scale = 0.125f * 0.25f; // 1/sqrt(64) * 1/sqrt(16)
    for (int base = blockIdx.x * 2; base < n_nodes; base += gridDim.x * 2) {
        int n = base + half;
        if (n >= n_nodes) continue;
        const float* __restrict__ mr = mid + (size_t)n * 256;
        float acc = 0.0f;
        if (j < 32) {
            #pragma unroll
            for (int u = 0; u < 32; u++)
                acc += mr[u] * sS0[u * 32 + j] + mr[32 + u] * sS1[u * 32 + j];
        } else {
            #pragma unroll
            for (int u = 0; u < 32; u++)
                acc += mr[64 + 3 * u + i] * sV0[u * 32 + w] + mr[160 + 3 * u + i] * sV1[u * 32 + w];
        }
        out[(size_t)n * 128 + j] = acc * (attr_out[n] * scale);
    }
}

extern "C" void kernel_launch(void* const* d_in, const int* in_sizes, int n_in,
                              void* d_out, int out_size, void* d_ws, size_t ws_size,
                              hipStream_t stream)
{
    const float* node_input = (const float*)d_in[0];
    const float* attr_in    = (const float*)d_in[1];
    const float* attr_out   = (const float*)d_in[2];
    const int*   esrc       = (const int*)d_in[3];
    const int*   edst       = (const int*)d_in[4];
    const float* eattr      = (const float*)d_in[5];
    const float* escal      = (const float*)d_in[6];
    const float* w1s        = (const float*)d_in[7];
    const float* w1v        = (const float*)d_in[8];
    const float* Wfc1       = (const float*)d_in[9];
    const float* Wfc2       = (const float*)d_in[10];
    const float* w2s        = (const float*)d_in[11];
    const float* w2v        = (const float*)d_in[12];
    float* out = (float*)d_out;

    int n_nodes = in_sizes[0] / 128;
    int n_edges = in_sizes[3];

    // workspace layout
    float* ws   = (float*)d_ws;
    float* xsv1 = ws;                                    // n_nodes*128
    float* W1s  = xsv1 + (size_t)n_nodes * 128;          // 512
    float* W2T  = W1s + 512;                             // 8192
    float* mid  = W2T + 8192;                            // n_nodes*256
    int*   counts = (int*)(mid + (size_t)n_nodes * 256); // n_nodes
    int*   offs   = counts + n_nodes;                    // n_nodes+1
    int*   cursor = offs + n_nodes + 1;                  // n_nodes
    int*   elist  = cursor + n_nodes;                    // n_edges
    unsigned short* wbuf = (unsigned short*)(elist + n_edges); // n_edges*128 bf16

    size_t needed = ((size_t)(elist + n_edges) - (size_t)d_ws) + (size_t)n_edges * 128 * 2;

    prep_kernel<<<32, 256, 0, stream>>>(Wfc1, Wfc2, W1s, W2T);
    node_in_kernel<<<2048, 256, 0, stream>>>(node_input, attr_in, w1s, w1v, xsv1, n_nodes);

    if (ws_size >= needed) {
        // CSR-gather path (no scattered fp32 atomics)
        hipMemsetAsync(counts, 0, (size_t)n_nodes * sizeof(int), stream);
        count_kernel<<<(n_edges + 255) / 256, 256, 0, stream>>>(edst, counts, n_edges);
        scan_kernel<<<1, 1024, 0, stream>>>(counts, offs, cursor, n_nodes);
        scatter_kernel<<<(n_edges + 255) / 256, 256, 0, stream>>>(edst, cursor, elist, n_edges);
        edge_mlp_kernel<<<(n_edges + 255) / 256, 256, 0, stream>>>(escal, W1s, W2T, wbuf, n_edges);
        gather_kernel<<<n_nodes, 256, 0, stream>>>(wbuf, xsv1, esrc, eattr, offs, elist, mid, n_nodes);
    } else {
        // fallback: atomic scatter-add
        hipMemsetAsync(mid, 0, (size_t)n_nodes * 256 * sizeof(float), stream);
        edge_kernel_atomic<<<(n_edges + 255) / 256, 256, 0, stream>>>(
            xsv1, esrc, edst, eattr, escal, W1s, W2T, mid, n_edges);
    }
    node_out_kernel<<<2048, 256, 0, stream>>>(mid, attr_out, w2s, w2v, out, n_nodes);
}